// Round 11
// baseline (151.484 us; speedup 1.0000x reference)
//
#include <hip/hip_runtime.h>
#include <math.h>

// Problem constants (fixed by setup_inputs)
#define B_  4
#define C_  256
#define W_  64
#define M_  4096          // ref locations (H*W)
#define N_  4096          // anchors per batch (== M_)
#define THRESH_ 0.4f      // relu(0.6 - dist) = relu(sim - 0.4)

typedef __attribute__((ext_vector_type(8))) short bf16x8;
typedef __attribute__((ext_vector_type(4))) float f32x4;

__device__ __forceinline__ short f2bf(float x) {       // RNE float->bf16
    union { float f; unsigned u; } v; v.f = x;
    unsigned r = v.u + 0x7fffu + ((v.u >> 16) & 1u);
    return (short)(r >> 16);
}
__device__ __forceinline__ float bf2f(short s) {
    union { unsigned u; float f; } v;
    v.u = ((unsigned)(unsigned short)s) << 16;
    return v.f;
}
__device__ __forceinline__ void gload_lds16(const void* g, void* l) {
    __builtin_amdgcn_global_load_lds(
        (const __attribute__((address_space(1))) void*)g,
        (__attribute__((address_space(3))) void*)l, 16, 0, 0);
}

// ---------------------------------------------------------------------------
// Workspace layout (bytes); identical to r10 (proven).
// ---------------------------------------------------------------------------
#define OFF_SKT    0
#define OFF_REFT   8388608
#define OFF_ISN    16777216
#define OFF_IR     16842752
#define OFF_FLAGC  16908288
#define OFF_FLAGL  16908544
#define OFF_DIAG   17170432
#define OFF_ROWSUM 17235968
#define OFF_ROWCNT 17301504
#define OFF_AIDX   17367040

// ---------- fused convert+transpose+norm+init (LDS-tiled, 1024 thr) --------
// block = (b, 64-row m-tile) x (z). 16 waves -> full CU occupancy (2 blk/CU).
// Same r9/r10 swizzle: phys chunk = ch ^ ((row>>2)&7); write 4-way max,
// read-out conflict-free, global writes fully coalesced.
#define RS_ 256

__global__ __launch_bounds__(1024) void convert_kernel(
    const float* __restrict__ sketch, const float* __restrict__ ref,
    short* __restrict__ sketchT, short* __restrict__ refT,
    const int* __restrict__ ay, const int* __restrict__ ax,
    float* __restrict__ isn, float* __restrict__ ir,
    int* __restrict__ aidx, float* __restrict__ rowsum,
    int* __restrict__ rowcnt, int* __restrict__ flagcnt)
{
    const int z  = blockIdx.y;
    const int b  = blockIdx.x >> 6;
    const int m0 = (blockIdx.x & 63) * 64;
    const int tid = threadIdx.x;
    const int lane = tid & 63, wv = tid >> 6;   // 16 waves
    const int lg = lane >> 4;                   // c-subgroup 0..3
    const int mloc = (lane & 15) * 4;           // 4 m-rows per lane
    const int key = lane & 7;                   // == ((mloc+e)>>2)&7

    __shared__ __align__(16) short Ts[64 * RS_];   // 32KB bf16 tile [m][c]
    __shared__ float ssp[16][64];

    const float* src = (z ? ref : sketch) + (size_t)b * C_ * M_ + m0 + mloc;
    float s0 = 0.f, s1 = 0.f, s2 = 0.f, s3 = 0.f;
#pragma unroll
    for (int i = 0; i < 4; ++i) {
        const int cc = wv * 16 + i * 4 + lg;
        const float4 v = *reinterpret_cast<const float4*>(src + (size_t)cc * M_);
        s0 += v.x * v.x; s1 += v.y * v.y; s2 += v.z * v.z; s3 += v.w * v.w;
        const int ch = cc >> 3, off = cc & 7;
        const int ph = ((ch ^ key) << 3) | off;
        Ts[(mloc + 0) * RS_ + ph] = f2bf(v.x);
        Ts[(mloc + 1) * RS_ + ph] = f2bf(v.y);
        Ts[(mloc + 2) * RS_ + ph] = f2bf(v.z);
        Ts[(mloc + 3) * RS_ + ph] = f2bf(v.w);
    }
    // reduce the 4 lg-groups within the wave
    s0 += __shfl_xor(s0, 16); s0 += __shfl_xor(s0, 32);
    s1 += __shfl_xor(s1, 16); s1 += __shfl_xor(s1, 32);
    s2 += __shfl_xor(s2, 16); s2 += __shfl_xor(s2, 32);
    s3 += __shfl_xor(s3, 16); s3 += __shfl_xor(s3, 32);
    if (lane < 16) {
        ssp[wv][mloc + 0] = s0; ssp[wv][mloc + 1] = s1;
        ssp[wv][mloc + 2] = s2; ssp[wv][mloc + 3] = s3;
    }
    if (z == 0 && blockIdx.x == 0 && tid == 64) *flagcnt = 0;
    __syncthreads();

    if (tid < 64) {
        float tot = 0.f;
#pragma unroll
        for (int w = 0; w < 16; ++w) tot += ssp[w][tid];
        const int gi = b * M_ + m0 + tid;
        if (z == 0) {
            isn[gi] = rsqrtf(tot);
            aidx[gi] = ay[gi] * W_ + ax[gi];
            rowsum[gi] = 0.f;
            rowcnt[gi] = 0;
        } else {
            ir[gi] = rsqrtf(tot);
        }
    }

    short* dst = (z ? refT : sketchT) + ((size_t)b * M_ + m0) * C_;
#pragma unroll
    for (int it = 0; it < 2; ++it) {
        const int g = it * 1024 + tid;
        const int r = g >> 5, ch = g & 31;
        const bf16x8 v = *reinterpret_cast<const bf16x8*>(
            &Ts[r * RS_ + ((ch ^ ((r >> 2) & 7)) << 3)]);
        *reinterpret_cast<bf16x8*>(dst + g * 8) = v;
    }
}

// ------------------------------ MFMA GEMM + fused epilogue -----------------
// Persistent 128x128: block owns m-panel (128 rows), streams 8 n-tiles x
// 4 K-tiles = 32 segments. 4 waves (2m x 2n), wave 64x64 (mf=4, nf=4).
// Buffers: A 3-deep + B 2-deep (16KB each) = 80KB -> 2 independent blocks/CU.
// Per segment: issue 4xB(seg+1) then 4xA(seg+2); boundary wait = vmcnt(4)
// (FIFO: only A(seg+2) may remain in flight) -- never a full drain in steady
// state. One s_barrier per segment. T2 swizzle + C/D map proven (r5/r8/r10).
#define BK 64
#define NKT 4    // K-tiles (C_/BK)
#define NTL 8    // n-tiles per block (8 x 128 = 1024 cols)

__global__ __launch_bounds__(256, 2) void gemm_kernel(
    const short* __restrict__ sketchT, const short* __restrict__ refT,
    const int* __restrict__ aidx,
    const float* __restrict__ isn, const float* __restrict__ ir,
    float* __restrict__ diag, float* __restrict__ rowsum,
    int* __restrict__ rowcnt)
{
    // 512 blocks: xcd-major decode; per XCD: one batch, 2 n-splits (~3MB L2)
    const int bid = blockIdx.x;
    const int xcd = bid & 7, slot = bid >> 3;
    const int b = xcd >> 1;
    const int mBase  = (slot >> 1) * 128;                 // 32 m-panels
    const int nsBase = ((xcd & 1) * 2 + (slot & 1)) * (NTL * 128);

    const int tid = threadIdx.x;
    const int lane = tid & 63, wv = tid >> 6;             // 4 waves
    const int wm = (wv >> 1) * 64, wn_ = (wv & 1) * 64;
    const int l15 = lane & 15, l4 = lane >> 4;
    const int l7 = lane & 7, l8 = lane >> 3;
    const int ksw = ((l7 ^ l8) << 3);                     // swizzled src k

    __shared__ __align__(16) short Ab[3][128 * BK];       // 3 x 16KB
    __shared__ __align__(16) short Bb[2][128 * BK];       // 2 x 16KB

    const short* Apanel = refT + ((size_t)b * M_ + mBase) * C_ + ksw;
    const short* Sbase  = sketchT + (size_t)b * M_ * C_ + ksw;
    const int* aidxb = aidx + b * N_;

    int arow[4];
#pragma unroll
    for (int q = 0; q < 4; ++q) arow[q] = (q * 4 + wv) * 8 + l8;  // 0..127

    int aic[4], ain[4];
#pragma unroll
    for (int q = 0; q < 4; ++q) aic[q] = aidxb[nsBase + arow[q]];

    f32x4 acc[4][4] = {};

    // prologue: B(0), A(0), A(1)  (issue order matters for vmcnt counting)
#pragma unroll
    for (int q = 0; q < 4; ++q)
        gload_lds16(Sbase + (size_t)aic[q] * C_, (char*)Bb[0] + (q * 4 + wv) * 1024);
#pragma unroll
    for (int q = 0; q < 4; ++q)
        gload_lds16(Apanel + (size_t)arow[q] * C_, (char*)Ab[0] + (q * 4 + wv) * 1024);
#pragma unroll
    for (int q = 0; q < 4; ++q)
        gload_lds16(Apanel + (size_t)arow[q] * C_ + BK, (char*)Ab[1] + (q * 4 + wv) * 1024);
    asm volatile("s_waitcnt vmcnt(4)" ::: "memory");      // B(0),A(0) landed
    __builtin_amdgcn_s_barrier();

    int bnt = 0;                                          // nt % 3
    for (int nt = 0; nt < NTL; ++nt) {
        const bool lastnt = (nt == NTL - 1);
        if (!lastnt) {                                    // prefetch next aidx
#pragma unroll
            for (int q = 0; q < 4; ++q)
                ain[q] = aidxb[nsBase + (nt + 1) * 128 + arow[q]];
        }
#pragma unroll
        for (int kt = 0; kt < NKT; ++kt) {
            int ba = bnt + kt;         if (ba >= 3) ba -= 3; if (ba >= 3) ba -= 3;
            int bs = bnt + kt + 2;     if (bs >= 3) bs -= 3; if (bs >= 3) bs -= 3;

            // stage B(seg+1) -> Bb[(kt+1)&1]
            if (!(lastnt && kt == 3)) {
                const int ktb = (kt + 1) & 3;
                const int* ai = (kt == 3) ? ain : aic;
#pragma unroll
                for (int q = 0; q < 4; ++q)
                    gload_lds16(Sbase + (size_t)ai[q] * C_ + ktb * BK,
                                (char*)Bb[(kt + 1) & 1] + (q * 4 + wv) * 1024);
            }
            // stage A(seg+2) -> Ab[bs]
            if (!(lastnt && kt >= 2)) {
                const int kta = (kt + 2) & 3;
#pragma unroll
                for (int q = 0; q < 4; ++q)
                    gload_lds16(Apanel + (size_t)arow[q] * C_ + kta * BK,
                                (char*)Ab[bs] + (q * 4 + wv) * 1024);
            }

            // fragment reads (compiler inserts lgkm waits before MFMA, so all
            // LDS reads retire before this wave's boundary barrier)
            bf16x8 pm[4][2], pn[4][2];
#pragma unroll
            for (int f = 0; f < 4; ++f)
#pragma unroll
                for (int ks = 0; ks < 2; ++ks) {
                    const int kph = ((ks * 4 + l4) ^ (l15 & 7)) << 3;
                    pm[f][ks] = *reinterpret_cast<const bf16x8*>(
                        &Ab[ba][(wm + f * 16 + l15) * BK + kph]);
                    pn[f][ks] = *reinterpret_cast<const bf16x8*>(
                        &Bb[kt & 1][(wn_ + f * 16 + l15) * BK + kph]);
                }
            __builtin_amdgcn_s_setprio(1);
#pragma unroll
            for (int mf = 0; mf < 4; ++mf)
#pragma unroll
                for (int nf = 0; nf < 4; ++nf)
#pragma unroll
                    for (int ks = 0; ks < 2; ++ks)
                        acc[mf][nf] = __builtin_amdgcn_mfma_f32_16x16x32_bf16(
                            pm[mf][ks], pn[nf][ks], acc[mf][nf], 0, 0, 0);
            __builtin_amdgcn_s_setprio(0);

            if (kt == 3) {
                // epilogue for n-tile nt (global-only ops; overlaps stages)
                const int nB = nsBase + nt * 128;
                float irv[4][4];
#pragma unroll
                for (int mf = 0; mf < 4; ++mf)
#pragma unroll
                    for (int r = 0; r < 4; ++r)
                        irv[mf][r] = ir[b * M_ + mBase + wm + mf * 16 + l4 * 4 + r];
#pragma unroll
                for (int nf = 0; nf < 4; ++nf) {
                    const int gn = nB + wn_ + nf * 16 + l15;
                    const float ian = isn[b * M_ + aidxb[gn]];
                    float s = 0.f; int cnt = 0;
#pragma unroll
                    for (int mf = 0; mf < 4; ++mf) {
#pragma unroll
                        for (int r = 0; r < 4; ++r) {
                            const int gm = mBase + wm + mf * 16 + l4 * 4 + r;
                            const float sim = acc[mf][nf][r] * irv[mf][r] * ian;
                            if (gm == gn) {
                                diag[b * N_ + gn] = 1.0f - sim;
                            } else if (sim > THRESH_) {
                                s += sim - THRESH_; ++cnt;
                            }
                        }
                    }
                    if (cnt) {
                        atomicAdd(&rowsum[b * N_ + gn], s);
                        atomicAdd(&rowcnt[b * N_ + gn], cnt);
                    }
                }
#pragma unroll
                for (int mf = 0; mf < 4; ++mf)
#pragma unroll
                    for (int nf = 0; nf < 4; ++nf)
                        acc[mf][nf] = (f32x4){0.f, 0.f, 0.f, 0.f};
            }

            // segment boundary: steady state waits vmcnt(4) (A(seg+2) flying)
            if (lastnt && kt >= 2) {
                asm volatile("s_waitcnt vmcnt(0)" ::: "memory");
            } else {
                asm volatile("s_waitcnt vmcnt(4)" ::: "memory");
            }
            __builtin_amdgcn_s_barrier();
        }
#pragma unroll
        for (int q = 0; q < 4; ++q) aic[q] = ain[q];
        bnt = (bnt == 2) ? 0 : bnt + 1;
    }
}

// ------------------------- flag rows needing exact top-4 -------------------
__global__ __launch_bounds__(256) void flag_kernel(
    const int* __restrict__ rowcnt, int* __restrict__ flagcnt,
    int* __restrict__ flaglist)
{
    int i = blockIdx.x * 256 + threadIdx.x;
    if (rowcnt[i] > 4) {
        int p = atomicAdd(flagcnt, 1);
        flaglist[p] = i;
    }
}

// -------- exact top-4 recompute for flagged rows (empty for this input) ----
__global__ __launch_bounds__(256) void fallback_kernel(
    const short* __restrict__ sketchT, const short* __restrict__ refT,
    const int* __restrict__ aidx,
    const float* __restrict__ isn, const float* __restrict__ ir,
    const int* __restrict__ flagcnt, const int* __restrict__ flaglist,
    float* __restrict__ rowsum)
{
    const int nflag = *flagcnt;
    __shared__ float av[C_];
    __shared__ float tops[256][4];
    for (int fi = blockIdx.x; fi < nflag; fi += gridDim.x) {
        const int row = flaglist[fi];
        const int b = row >> 12, n = row & (N_ - 1);
        const int an = aidx[row];
        __syncthreads();
        av[threadIdx.x] = bf2f(sketchT[((size_t)b * M_ + an) * C_ + threadIdx.x]);
        __syncthreads();
        const float ian = isn[b * M_ + an];
        float t0 = 0, t1 = 0, t2 = 0, t3 = 0;
        for (int m = threadIdx.x; m < M_; m += 256) {
            if (m == n) continue;
            const short* rp = refT + ((size_t)b * M_ + m) * C_;
            float dot = 0.f;
#pragma unroll 8
            for (int c = 0; c < C_; ++c) dot += av[c] * bf2f(rp[c]);
            float rl = dot * ian * ir[b * M_ + m] - THRESH_;
            if (rl > t3) {
                t3 = rl;
                if (t3 > t2) { float t = t2; t2 = t3; t3 = t; }
                if (t2 > t1) { float t = t1; t1 = t2; t2 = t; }
                if (t1 > t0) { float t = t0; t0 = t1; t1 = t; }
            }
        }
        tops[threadIdx.x][0] = t0; tops[threadIdx.x][1] = t1;
        tops[threadIdx.x][2] = t2; tops[threadIdx.x][3] = t3;
        __syncthreads();
        if (threadIdx.x == 0) {
            float s0 = 0, s1 = 0, s2 = 0, s3 = 0;
            for (int t = 0; t < 1024; ++t) {
                float v = tops[t >> 2][t & 3];
                if (v > s3) {
                    s3 = v;
                    if (s3 > s2) { float tt = s2; s2 = s3; s3 = tt; }
                    if (s2 > s1) { float tt = s1; s1 = s2; s2 = tt; }
                    if (s1 > s0) { float tt = s0; s0 = s1; s1 = tt; }
                }
            }
            rowsum[row] = s0 + s1 + s2 + s3;
        }
        __syncthreads();
    }
}

// ------------------------------ final reduce -------------------------------
__global__ __launch_bounds__(256) void final_kernel(
    const float* __restrict__ rowsum, const float* __restrict__ diag,
    float* __restrict__ out)
{
    float sn = 0.f, sp = 0.f;
    for (int i = threadIdx.x; i < B_ * N_; i += 256) {
        sn += rowsum[i];
        sp += diag[i];
    }
    __shared__ float red[256];
    red[threadIdx.x] = sp * (1.0f / (B_ * N_)) + sn * (1.0f / (B_ * N_ * 4));
    __syncthreads();
    for (int s = 128; s > 0; s >>= 1) {
        if (threadIdx.x < s) red[threadIdx.x] += red[threadIdx.x + s];
        __syncthreads();
    }
    if (threadIdx.x == 0) out[0] = red[0];
}

// ---------------------------------------------------------------------------
extern "C" void kernel_launch(void* const* d_in, const int* in_sizes, int n_in,
                              void* d_out, int out_size, void* d_ws, size_t ws_size,
                              hipStream_t stream)
{
    const float* sketch = (const float*)d_in[0];
    const float* ref    = (const float*)d_in[1];
    const int*   ay     = (const int*)d_in[2];
    const int*   ax     = (const int*)d_in[3];
    float* out = (float*)d_out;

    char* ws = (char*)d_ws;
    short* sketchT  = (short*)(ws + OFF_SKT);
    short* refT     = (short*)(ws + OFF_REFT);
    float* isn      = (float*)(ws + OFF_ISN);
    float* ir       = (float*)(ws + OFF_IR);
    int*   flagcnt  = (int*)(ws + OFF_FLAGC);
    int*   flaglist = (int*)(ws + OFF_FLAGL);
    float* diag     = (float*)(ws + OFF_DIAG);
    float* rowsum   = (float*)(ws + OFF_ROWSUM);
    int*   rowcnt   = (int*)(ws + OFF_ROWCNT);
    int*   aidx     = (int*)(ws + OFF_AIDX);

    convert_kernel<<<dim3(64 * B_, 2), 1024, 0, stream>>>(
        sketch, ref, sketchT, refT, ay, ax, isn, ir, aidx,
        rowsum, rowcnt, flagcnt);

    gemm_kernel<<<512, 256, 0, stream>>>(
        sketchT, refT, aidx, isn, ir, diag, rowsum, rowcnt);

    flag_kernel<<<(B_ * N_) / 256, 256, 0, stream>>>(rowcnt, flagcnt, flaglist);
    fallback_kernel<<<64, 256, 0, stream>>>(sketchT, refT, aidx, isn, ir,
                                            flagcnt, flaglist, rowsum);
    final_kernel<<<1, 256, 0, stream>>>(rowsum, diag, out);
}

// Round 13
// 141.406 us; speedup vs baseline: 1.0713x; 1.0713x over previous
//
#include <hip/hip_runtime.h>
#include <math.h>

// Problem constants (fixed by setup_inputs)
#define B_  4
#define C_  256
#define W_  64
#define M_  4096          // ref locations (H*W)
#define N_  4096          // anchors per batch (== M_)
#define THRESH_ 0.4f      // relu(0.6 - dist) = relu(sim - 0.4)

typedef __attribute__((ext_vector_type(8))) short bf16x8;
typedef __attribute__((ext_vector_type(4))) float f32x4;

__device__ __forceinline__ short f2bf(float x) {       // RNE float->bf16
    union { float f; unsigned u; } v; v.f = x;
    unsigned r = v.u + 0x7fffu + ((v.u >> 16) & 1u);
    return (short)(r >> 16);
}
__device__ __forceinline__ float bf2f(short s) {
    union { unsigned u; float f; } v;
    v.u = ((unsigned)(unsigned short)s) << 16;
    return v.f;
}
__device__ __forceinline__ void gload_lds16(const void* g, void* l) {
    __builtin_amdgcn_global_load_lds(
        (const __attribute__((address_space(1))) void*)g,
        (__attribute__((address_space(3))) void*)l, 16, 0, 0);
}

// ---------------------------------------------------------------------------
// Workspace layout (bytes); subset of the r10/r11-proven layout.
// ---------------------------------------------------------------------------
#define OFF_SKT    0
#define OFF_REFT   8388608
#define OFF_ISN    16777216
#define OFF_IR     16842752
#define OFF_DIAG   17170432
#define OFF_ROWSUM 17235968
#define OFF_ROWCNT 17301504
#define OFF_AIDX   17367040

// ---------- fused convert+transpose+norm+init (LDS-tiled, 1024 thr) --------
// [r11-proven, absmax 0.0] block = (b, 64-row m-tile) x (z). Swizzle:
// phys chunk = ch ^ ((row>>2)&7); write 4-way max, read-out conflict-free,
// global writes fully coalesced. Column norms finalize in-block.
#define RS_ 256

__global__ __launch_bounds__(1024) void convert_kernel(
    const float* __restrict__ sketch, const float* __restrict__ ref,
    short* __restrict__ sketchT, short* __restrict__ refT,
    const int* __restrict__ ay, const int* __restrict__ ax,
    float* __restrict__ isn, float* __restrict__ ir,
    int* __restrict__ aidx, float* __restrict__ rowsum,
    int* __restrict__ rowcnt)
{
    const int z  = blockIdx.y;
    const int b  = blockIdx.x >> 6;
    const int m0 = (blockIdx.x & 63) * 64;
    const int tid = threadIdx.x;
    const int lane = tid & 63, wv = tid >> 6;   // 16 waves
    const int lg = lane >> 4;                   // c-subgroup 0..3
    const int mloc = (lane & 15) * 4;           // 4 m-rows per lane
    const int key = lane & 7;                   // == ((mloc+e)>>2)&7

    __shared__ __align__(16) short Ts[64 * RS_];   // 32KB bf16 tile [m][c]
    __shared__ float ssp[16][64];

    const float* src = (z ? ref : sketch) + (size_t)b * C_ * M_ + m0 + mloc;
    float s0 = 0.f, s1 = 0.f, s2 = 0.f, s3 = 0.f;
#pragma unroll
    for (int i = 0; i < 4; ++i) {
        const int cc = wv * 16 + i * 4 + lg;
        const float4 v = *reinterpret_cast<const float4*>(src + (size_t)cc * M_);
        s0 += v.x * v.x; s1 += v.y * v.y; s2 += v.z * v.z; s3 += v.w * v.w;
        const int ch = cc >> 3, off = cc & 7;
        const int ph = ((ch ^ key) << 3) | off;
        Ts[(mloc + 0) * RS_ + ph] = f2bf(v.x);
        Ts[(mloc + 1) * RS_ + ph] = f2bf(v.y);
        Ts[(mloc + 2) * RS_ + ph] = f2bf(v.z);
        Ts[(mloc + 3) * RS_ + ph] = f2bf(v.w);
    }
    s0 += __shfl_xor(s0, 16); s0 += __shfl_xor(s0, 32);
    s1 += __shfl_xor(s1, 16); s1 += __shfl_xor(s1, 32);
    s2 += __shfl_xor(s2, 16); s2 += __shfl_xor(s2, 32);
    s3 += __shfl_xor(s3, 16); s3 += __shfl_xor(s3, 32);
    if (lane < 16) {
        ssp[wv][mloc + 0] = s0; ssp[wv][mloc + 1] = s1;
        ssp[wv][mloc + 2] = s2; ssp[wv][mloc + 3] = s3;
    }
    __syncthreads();

    if (tid < 64) {
        float tot = 0.f;
#pragma unroll
        for (int w = 0; w < 16; ++w) tot += ssp[w][tid];
        const int gi = b * M_ + m0 + tid;
        if (z == 0) {
            isn[gi] = rsqrtf(tot);
            aidx[gi] = ay[gi] * W_ + ax[gi];
            rowsum[gi] = 0.f;
            rowcnt[gi] = 0;
        } else {
            ir[gi] = rsqrtf(tot);
        }
    }

    short* dst = (z ? refT : sketchT) + ((size_t)b * M_ + m0) * C_;
#pragma unroll
    for (int it = 0; it < 2; ++it) {
        const int g = it * 1024 + tid;
        const int r = g >> 5, ch = g & 31;
        const bf16x8 v = *reinterpret_cast<const bf16x8*>(
            &Ts[r * RS_ + ((ch ^ ((r >> 2) & 7)) << 3)]);
        *reinterpret_cast<bf16x8*>(dst + g * 8) = v;
    }
}

// ------------------------------ MFMA GEMM + fused epilogue -----------------
// [r11-proven, absmax 0.0] Persistent 128x128, 4 waves, A 3-deep + B 2-deep,
// counted vmcnt(4) boundaries, T2 swizzle, fused cosine+diag+relu epilogue.
#define BK 64
#define NKT 4
#define NTL 8

__global__ __launch_bounds__(256, 2) void gemm_kernel(
    const short* __restrict__ sketchT, const short* __restrict__ refT,
    const int* __restrict__ aidx,
    const float* __restrict__ isn, const float* __restrict__ ir,
    float* __restrict__ diag, float* __restrict__ rowsum,
    int* __restrict__ rowcnt)
{
    const int bid = blockIdx.x;
    const int xcd = bid & 7, slot = bid >> 3;
    const int b = xcd >> 1;
    const int mBase  = (slot >> 1) * 128;
    const int nsBase = ((xcd & 1) * 2 + (slot & 1)) * (NTL * 128);

    const int tid = threadIdx.x;
    const int lane = tid & 63, wv = tid >> 6;
    const int wm = (wv >> 1) * 64, wn_ = (wv & 1) * 64;
    const int l15 = lane & 15, l4 = lane >> 4;
    const int l7 = lane & 7, l8 = lane >> 3;
    const int ksw = ((l7 ^ l8) << 3);

    __shared__ __align__(16) short Ab[3][128 * BK];
    __shared__ __align__(16) short Bb[2][128 * BK];

    const short* Apanel = refT + ((size_t)b * M_ + mBase) * C_ + ksw;
    const short* Sbase  = sketchT + (size_t)b * M_ * C_ + ksw;
    const int* aidxb = aidx + b * N_;

    int arow[4];
#pragma unroll
    for (int q = 0; q < 4; ++q) arow[q] = (q * 4 + wv) * 8 + l8;

    int aic[4], ain[4];
#pragma unroll
    for (int q = 0; q < 4; ++q) aic[q] = aidxb[nsBase + arow[q]];

    f32x4 acc[4][4] = {};

#pragma unroll
    for (int q = 0; q < 4; ++q)
        gload_lds16(Sbase + (size_t)aic[q] * C_, (char*)Bb[0] + (q * 4 + wv) * 1024);
#pragma unroll
    for (int q = 0; q < 4; ++q)
        gload_lds16(Apanel + (size_t)arow[q] * C_, (char*)Ab[0] + (q * 4 + wv) * 1024);
#pragma unroll
    for (int q = 0; q < 4; ++q)
        gload_lds16(Apanel + (size_t)arow[q] * C_ + BK, (char*)Ab[1] + (q * 4 + wv) * 1024);
    asm volatile("s_waitcnt vmcnt(4)" ::: "memory");
    __builtin_amdgcn_s_barrier();

    int bnt = 0;
    for (int nt = 0; nt < NTL; ++nt) {
        const bool lastnt = (nt == NTL - 1);
        if (!lastnt) {
#pragma unroll
            for (int q = 0; q < 4; ++q)
                ain[q] = aidxb[nsBase + (nt + 1) * 128 + arow[q]];
        }
#pragma unroll
        for (int kt = 0; kt < NKT; ++kt) {
            int ba = bnt + kt;     if (ba >= 3) ba -= 3; if (ba >= 3) ba -= 3;
            int bs = bnt + kt + 2; if (bs >= 3) bs -= 3; if (bs >= 3) bs -= 3;

            if (!(lastnt && kt == 3)) {
                const int ktb = (kt + 1) & 3;
                const int* ai = (kt == 3) ? ain : aic;
#pragma unroll
                for (int q = 0; q < 4; ++q)
                    gload_lds16(Sbase + (size_t)ai[q] * C_ + ktb * BK,
                                (char*)Bb[(kt + 1) & 1] + (q * 4 + wv) * 1024);
            }
            if (!(lastnt && kt >= 2)) {
                const int kta = (kt + 2) & 3;
#pragma unroll
                for (int q = 0; q < 4; ++q)
                    gload_lds16(Apanel + (size_t)arow[q] * C_ + kta * BK,
                                (char*)Ab[bs] + (q * 4 + wv) * 1024);
            }

            bf16x8 pm[4][2], pn[4][2];
#pragma unroll
            for (int f = 0; f < 4; ++f)
#pragma unroll
                for (int ks = 0; ks < 2; ++ks) {
                    const int kph = ((ks * 4 + l4) ^ (l15 & 7)) << 3;
                    pm[f][ks] = *reinterpret_cast<const bf16x8*>(
                        &Ab[ba][(wm + f * 16 + l15) * BK + kph]);
                    pn[f][ks] = *reinterpret_cast<const bf16x8*>(
                        &Bb[kt & 1][(wn_ + f * 16 + l15) * BK + kph]);
                }
            __builtin_amdgcn_s_setprio(1);
#pragma unroll
            for (int mf = 0; mf < 4; ++mf)
#pragma unroll
                for (int nf = 0; nf < 4; ++nf)
#pragma unroll
                    for (int ks = 0; ks < 2; ++ks)
                        acc[mf][nf] = __builtin_amdgcn_mfma_f32_16x16x32_bf16(
                            pm[mf][ks], pn[nf][ks], acc[mf][nf], 0, 0, 0);
            __builtin_amdgcn_s_setprio(0);

            if (kt == 3) {
                const int nB = nsBase + nt * 128;
                float irv[4][4];
#pragma unroll
                for (int mf = 0; mf < 4; ++mf)
#pragma unroll
                    for (int r = 0; r < 4; ++r)
                        irv[mf][r] = ir[b * M_ + mBase + wm + mf * 16 + l4 * 4 + r];
#pragma unroll
                for (int nf = 0; nf < 4; ++nf) {
                    const int gn = nB + wn_ + nf * 16 + l15;
                    const float ian = isn[b * M_ + aidxb[gn]];
                    float s = 0.f; int cnt = 0;
#pragma unroll
                    for (int mf = 0; mf < 4; ++mf) {
#pragma unroll
                        for (int r = 0; r < 4; ++r) {
                            const int gm = mBase + wm + mf * 16 + l4 * 4 + r;
                            const float sim = acc[mf][nf][r] * irv[mf][r] * ian;
                            if (gm == gn) {
                                diag[b * N_ + gn] = 1.0f - sim;
                            } else if (sim > THRESH_) {
                                s += sim - THRESH_; ++cnt;
                            }
                        }
                    }
                    if (cnt) {
                        atomicAdd(&rowsum[b * N_ + gn], s);
                        atomicAdd(&rowcnt[b * N_ + gn], cnt);
                    }
                }
#pragma unroll
                for (int mf = 0; mf < 4; ++mf)
#pragma unroll
                    for (int nf = 0; nf < 4; ++nf)
                        acc[mf][nf] = (f32x4){0.f, 0.f, 0.f, 0.f};
            }

            if (lastnt && kt >= 2) {
                asm volatile("s_waitcnt vmcnt(0)" ::: "memory");
            } else {
                asm volatile("s_waitcnt vmcnt(4)" ::: "memory");
            }
            __builtin_amdgcn_s_barrier();
        }
#pragma unroll
        for (int q = 0; q < 4; ++q) aic[q] = ain[q];
        bnt = (bnt == 2) ? 0 : bnt + 1;
    }
}

// ---------------- tail: flag-scan + exact top-4 fix + final reduce ---------
// ONE block, 1024 threads: scans rowcnt in 4 passes, block-locally fixes any
// row with >4 above-threshold sims (exact top-4; empty for this input), then
// reduces diag+rowsum. Single-block => __syncthreads orders fix before read.
__global__ __launch_bounds__(1024) void tail_kernel(
    const short* __restrict__ sketchT, const short* __restrict__ refT,
    const int* __restrict__ aidx,
    const float* __restrict__ isn, const float* __restrict__ ir,
    const int* __restrict__ rowcnt, float* __restrict__ rowsum,
    const float* __restrict__ diag, float* __restrict__ out)
{
    __shared__ int lst[4096];
    __shared__ int lcnt;
    __shared__ float av[C_];
    __shared__ float tops[1024][4];
    const int tid = threadIdx.x;

    for (int pass = 0; pass < 4; ++pass) {
        if (tid == 0) lcnt = 0;
        __syncthreads();
#pragma unroll
        for (int j = 0; j < 4; ++j) {
            const int rr = pass * 4096 + j * 1024 + tid;
            if (rowcnt[rr] > 4) { int p = atomicAdd(&lcnt, 1); lst[p] = rr; }
        }
        __syncthreads();
        const int nf = lcnt;
        for (int fi = 0; fi < nf; ++fi) {
            const int row = lst[fi];
            const int b = row >> 12, n = row & (N_ - 1);
            const int an = aidx[row];
            if (tid < C_) av[tid] = bf2f(sketchT[((size_t)b * M_ + an) * C_ + tid]);
            __syncthreads();
            const float ian = isn[b * M_ + an];
            float t0 = 0, t1 = 0, t2 = 0, t3 = 0;
            for (int m = tid; m < M_; m += 1024) {
                if (m == n) continue;
                const short* rp = refT + ((size_t)b * M_ + m) * C_;
                float dot = 0.f;
#pragma unroll 8
                for (int c = 0; c < C_; ++c) dot += av[c] * bf2f(rp[c]);
                float rl = dot * ian * ir[b * M_ + m] - THRESH_;
                if (rl > t3) {
                    t3 = rl;
                    if (t3 > t2) { float t = t2; t2 = t3; t3 = t; }
                    if (t2 > t1) { float t = t1; t1 = t2; t2 = t; }
                    if (t1 > t0) { float t = t0; t0 = t1; t1 = t; }
                }
            }
            tops[tid][0] = t0; tops[tid][1] = t1;
            tops[tid][2] = t2; tops[tid][3] = t3;
            __syncthreads();
            if (tid == 0) {
                float s0 = 0, s1 = 0, s2 = 0, s3 = 0;
                for (int t = 0; t < 4096; ++t) {
                    float v = tops[t >> 2][t & 3];
                    if (v > s3) {
                        s3 = v;
                        if (s3 > s2) { float tt = s2; s2 = s3; s3 = tt; }
                        if (s2 > s1) { float tt = s1; s1 = s2; s2 = tt; }
                        if (s1 > s0) { float tt = s0; s0 = s1; s1 = tt; }
                    }
                }
                rowsum[row] = s0 + s1 + s2 + s3;
            }
            __syncthreads();
        }
        __syncthreads();
    }

    // final reduce (rowsum fixes above are ordered by __syncthreads)
    float sn = 0.f, sp = 0.f;
    for (int i = tid; i < B_ * N_; i += 1024) {
        sn += rowsum[i];
        sp += diag[i];
    }
    __shared__ float red[1024];
    red[tid] = sp * (1.0f / (B_ * N_)) + sn * (1.0f / (B_ * N_ * 4));
    __syncthreads();
    for (int s = 512; s > 0; s >>= 1) {
        if (tid < s) red[tid] += red[tid + s];
        __syncthreads();
    }
    if (tid == 0) out[0] = red[0];
}

// ---------------------------------------------------------------------------
extern "C" void kernel_launch(void* const* d_in, const int* in_sizes, int n_in,
                              void* d_out, int out_size, void* d_ws, size_t ws_size,
                              hipStream_t stream)
{
    const float* sketch = (const float*)d_in[0];
    const float* ref    = (const float*)d_in[1];
    const int*   ay     = (const int*)d_in[2];
    const int*   ax     = (const int*)d_in[3];
    float* out = (float*)d_out;

    char* ws = (char*)d_ws;
    short* sketchT  = (short*)(ws + OFF_SKT);
    short* refT     = (short*)(ws + OFF_REFT);
    float* isn      = (float*)(ws + OFF_ISN);
    float* ir       = (float*)(ws + OFF_IR);
    float* diag     = (float*)(ws + OFF_DIAG);
    float* rowsum   = (float*)(ws + OFF_ROWSUM);
    int*   rowcnt   = (int*)(ws + OFF_ROWCNT);
    int*   aidx     = (int*)(ws + OFF_AIDX);

    convert_kernel<<<dim3(64 * B_, 2), 1024, 0, stream>>>(
        sketch, ref, sketchT, refT, ay, ax, isn, ir, aidx, rowsum, rowcnt);

    gemm_kernel<<<512, 256, 0, stream>>>(
        sketchT, refT, aidx, isn, ir, diag, rowsum, rowcnt);

    tail_kernel<<<1, 1024, 0, stream>>>(
        sketchT, refT, aidx, isn, ir, rowcnt, rowsum, diag, out);
}